// Round 1
// baseline (35110.080 us; speedup 1.0000x reference)
//
#include <hip/hip_runtime.h>
#include <math.h>

// GRU scan: B=64, L=2048, H=512, IN=1.
// Grid: 256 blocks x 512 threads. 8 groups x 32 blocks.
// Group g owns batches [8g, 8g+8); block j in group owns h-slice [16j, 16j+16)
// (48 rows of W_hh: 3 gates x 16 h), held in LDS for the whole kernel.
// Residual exchanged through d_ws (double buffer) with a per-group
// monotonic-epoch barrier (device-scope atomics at MALL).

#define BB_ 64
#define LL_ 2048
#define HH_ 512
#define NGROUP 8
#define GBLK 32     // blocks per group
#define BGRP 8      // batches per group
#define HBLK 16     // h per block
#define NT 512      // threads per block

template<int CTRL>
__device__ __forceinline__ float dpp_add(float x) {
    int s = __builtin_amdgcn_update_dpp(0, __float_as_int(x), CTRL, 0xF, 0xF, true);
    return x + __int_as_float(s);
}

__global__ __launch_bounds__(NT, 2)
void gru_scan_kernel(const float* __restrict__ x,
                     const float* __restrict__ state,
                     const float* __restrict__ W_ih,
                     const float* __restrict__ W_hh,
                     const float* __restrict__ b_ih,
                     const float* __restrict__ b_hh,
                     const float* __restrict__ A,
                     float* __restrict__ out,
                     char* __restrict__ ws) {
    __shared__ float W_s[48][HH_];     // 98304 B, stationary
    __shared__ float res_s[BGRP][HH_]; // 16384 B, restaged every step
    __shared__ float x_s[BGRP][128];   // 4096 B, restaged every 128 steps
    __shared__ float wih_s[48], bih_s[48], bhh_s[48];

    const int tid = threadIdx.x;
    const int bid = blockIdx.x;
    const int g   = bid >> 5;       // group
    const int j   = bid & 31;       // h-slice within group
    const int b0  = g * BGRP;
    const int h0  = j * HBLK;

    const int w    = tid >> 6;      // wave 0..7 -> h-pair {2w, 2w+1}
    const int lane = tid & 63;
    const int bg   = lane >> 4;     // batch-pair 0..3 -> b in {2bg, 2bg+1}
    const int ksub = lane & 15;     // k split 16-way

    unsigned* ctr = (unsigned*)ws + g * 16;        // 64B-spaced counters
    float* resA = (float*)(ws + 4096);             // [B][H]
    float* resB = resA + BB_ * HH_;                // [B][H]

    // ---- stage stationary data ----
    #pragma unroll
    for (int gg = 0; gg < 3; ++gg)
        for (int i = tid; i < HBLK * HH_; i += NT) {
            int hl = i >> 9, k = i & 511;
            W_s[gg * 16 + hl][k] = W_hh[(size_t)(gg * HH_ + h0 + hl) * HH_ + k];
        }
    for (int i = tid; i < 48; i += NT) {
        int gg = i >> 4, hl = i & 15;
        int row = gg * HH_ + h0 + hl;
        wih_s[i] = W_ih[row];   // IN == 1
        bih_s[i] = b_ih[row];
        bhh_s[i] = b_hh[row];
    }
    const float Aval = A[0];

    // st accumulator lives on ksub==15 lanes: [bl][hh]
    float st[2][2];
    #pragma unroll
    for (int bl = 0; bl < 2; ++bl)
        #pragma unroll
        for (int hh = 0; hh < 2; ++hh)
            st[bl][hh] = state[(size_t)(b0 + 2 * bg + bl) * HH_ + h0 + 2 * w + hh];

    const float4* W4 = (const float4*)&W_s[0][0];
    const float4* R4 = (const float4*)&res_s[0][0];

    for (int t = 0; t < LL_; ++t) {
        // ---- stage x tile every 128 steps ----
        if ((t & 127) == 0) {
            for (int i = tid; i < BGRP * 128; i += NT) {
                int bb = i >> 7, kk = i & 127;
                x_s[bb][kk] = x[(size_t)(b0 + bb) * LL_ + t + kk];
            }
        }
        // ---- stage residual (8 b x 512) ----
        {
            float rv[BGRP];
            if (t == 0) {
                #pragma unroll
                for (int jj = 0; jj < BGRP; ++jj)
                    rv[jj] = state[(size_t)(b0 + jj) * HH_ + tid];
            } else {
                const float* rbuf = (t & 1) ? resB : resA;
                #pragma unroll
                for (int jj = 0; jj < BGRP; ++jj)
                    rv[jj] = __hip_atomic_load(&rbuf[(size_t)(b0 + jj) * HH_ + tid],
                                               __ATOMIC_RELAXED, __HIP_MEMORY_SCOPE_AGENT);
            }
            #pragma unroll
            for (int jj = 0; jj < BGRP; ++jj)
                res_s[jj][tid] = rv[jj];
        }
        __syncthreads();

        // ---- residual fragment to registers: 2 b x 8 chunks of float4 ----
        float4 rv4[2][8];
        #pragma unroll
        for (int bl = 0; bl < 2; ++bl)
            #pragma unroll
            for (int m = 0; m < 8; ++m)
                rv4[bl][m] = R4[(2 * bg + bl) * 128 + m * 16 + ksub];

        // ---- GEMM slice: acc[row6][bl2], k-partial over this lane's 32 k ----
        float acc[6][2];
        #pragma unroll
        for (int rr = 0; rr < 6; ++rr) { acc[rr][0] = 0.f; acc[rr][1] = 0.f; }

        #pragma unroll
        for (int rr = 0; rr < 6; ++rr) {
            const int gg = rr >> 1, hh = rr & 1;
            const int lr = gg * 16 + 2 * w + hh;
            #pragma unroll
            for (int m = 0; m < 8; ++m) {
                float4 wv = W4[lr * 128 + m * 16 + ksub];
                #pragma unroll
                for (int bl = 0; bl < 2; ++bl) {
                    float4 r = rv4[bl][m];
                    acc[rr][bl] += wv.x * r.x + wv.y * r.y + wv.z * r.z + wv.w * r.w;
                }
            }
        }

        // ---- reduce over ksub (16 lanes) via DPP row_shr; sum -> ksub==15 ----
        #pragma unroll
        for (int rr = 0; rr < 6; ++rr)
            #pragma unroll
            for (int bl = 0; bl < 2; ++bl) {
                float v = acc[rr][bl];
                v = dpp_add<0x111>(v);  // row_shr:1
                v = dpp_add<0x112>(v);  // row_shr:2
                v = dpp_add<0x114>(v);  // row_shr:4
                v = dpp_add<0x118>(v);  // row_shr:8
                acc[rr][bl] = v;
            }

        // ---- gates on ksub==15 lanes (4 per wave, 4 (b,h) outputs each) ----
        if (ksub == 15) {
            float* wbuf = (t & 1) ? resA : resB;
            #pragma unroll
            for (int bl = 0; bl < 2; ++bl) {
                const int b = 2 * bg + bl;
                const int bglob = b0 + b;
                const float xv = x_s[b][t & 127];
                #pragma unroll
                for (int hh = 0; hh < 2; ++hh) {
                    const int hl = 2 * w + hh;
                    const int hglob = h0 + hl;
                    float hr = acc[hh][bl]     + bhh_s[hl];
                    float hz = acc[2 + hh][bl] + bhh_s[16 + hl];
                    float hn = acc[4 + hh][bl] + bhh_s[32 + hl];
                    float ir = xv * wih_s[hl]      + bih_s[hl];
                    float iz = xv * wih_s[16 + hl] + bih_s[16 + hl];
                    float in_ = xv * wih_s[32 + hl] + bih_s[32 + hl];
                    float r = 1.f / (1.f + __expf(-(ir + hr)));
                    float z = 1.f / (1.f + __expf(-(iz + hz)));
                    float n = tanhf(in_ + r * hn);
                    float oldr = res_s[b][hglob];
                    float nr = (1.f - z) * n + z * oldr;
                    st[bl][hh] += Aval * nr;
                    __hip_atomic_store(&wbuf[(size_t)bglob * HH_ + hglob], nr,
                                       __ATOMIC_RELAXED, __HIP_MEMORY_SCOPE_AGENT);
                    out[((size_t)bglob * LL_ + t) * HH_ + hglob] = st[bl][hh];
                }
            }
        }

        // ---- group barrier (32 blocks, monotonic epoch) ----
        __syncthreads();   // drains vmcnt: residual stores are at MALL
        if (tid == 0) {
            __hip_atomic_fetch_add(ctr, 1u, __ATOMIC_RELEASE, __HIP_MEMORY_SCOPE_AGENT);
            const unsigned target = (unsigned)(t + 1) * GBLK;
            while (__hip_atomic_load(ctr, __ATOMIC_RELAXED, __HIP_MEMORY_SCOPE_AGENT) < target)
                __builtin_amdgcn_s_sleep(1);
            __threadfence();
        }
        __syncthreads();
    }

    // ---- final state ----
    if (ksub == 15) {
        #pragma unroll
        for (int bl = 0; bl < 2; ++bl)
            #pragma unroll
            for (int hh = 0; hh < 2; ++hh) {
                const int bglob = b0 + 2 * bg + bl;
                const int hglob = h0 + 2 * w + hh;
                out[(size_t)BB_ * LL_ * HH_ + (size_t)bglob * HH_ + hglob] = st[bl][hh];
            }
    }
}

extern "C" void kernel_launch(void* const* d_in, const int* in_sizes, int n_in,
                              void* d_out, int out_size, void* d_ws, size_t ws_size,
                              hipStream_t stream) {
    (void)in_sizes; (void)n_in; (void)out_size; (void)ws_size;
    const float* x     = (const float*)d_in[0];
    const float* state = (const float*)d_in[1];
    const float* W_ih  = (const float*)d_in[2];
    const float* W_hh  = (const float*)d_in[3];
    const float* b_ih  = (const float*)d_in[4];
    const float* b_hh  = (const float*)d_in[5];
    const float* A     = (const float*)d_in[6];

    // zero the barrier counters (d_ws is re-poisoned to 0xAA before every launch)
    hipMemsetAsync(d_ws, 0, 4096, stream);
    hipLaunchKernelGGL(gru_scan_kernel, dim3(NGROUP * GBLK), dim3(NT), 0, stream,
                       x, state, W_ih, W_hh, b_ih, b_hh, A,
                       (float*)d_out, (char*)d_ws);
}

// Round 2
// 23949.118 us; speedup vs baseline: 1.4660x; 1.4660x over previous
//
#include <hip/hip_runtime.h>
#include <math.h>

// GRU scan: B=64, L=2048, H=512, IN=1.
// Grid: 256 blocks x 512 threads. 8 groups x 32 blocks.
// Group g owns batches [8g, 8g+8); block j in group owns h-slice [16j, 16j+16)
// (48 rows of W_hh: 3 gates x 16 h), held in LDS for the whole kernel.
// Residual exchanged through d_ws (double buffer).
//
// R2 change: the group barrier is now a per-block FLAG ARRAY (128B-padded
// slots) polled by wave 0 with one lane per slot + __all ballot. R1's single
// hot atomic counter + 31 pollers on the same MALL line serialized the whole
// step (~12 us/step idle; VALUBusy 15.5%).

#define BB_ 64
#define LL_ 2048
#define HH_ 512
#define NGROUP 8
#define GBLK 32     // blocks per group
#define BGRP 8      // batches per group
#define HBLK 16     // h per block
#define NT 512      // threads per block

#define FLAG_STRIDE 32            // dwords (128 B) per flag slot
#define FLAG_BYTES (NGROUP * GBLK * FLAG_STRIDE * 4)   // 32 KiB

template<int CTRL>
__device__ __forceinline__ float dpp_add(float x) {
    int s = __builtin_amdgcn_update_dpp(0, __float_as_int(x), CTRL, 0xF, 0xF, true);
    return x + __int_as_float(s);
}

__global__ __launch_bounds__(NT, 2)
void gru_scan_kernel(const float* __restrict__ x,
                     const float* __restrict__ state,
                     const float* __restrict__ W_ih,
                     const float* __restrict__ W_hh,
                     const float* __restrict__ b_ih,
                     const float* __restrict__ b_hh,
                     const float* __restrict__ A,
                     float* __restrict__ out,
                     char* __restrict__ ws) {
    __shared__ float W_s[48][HH_];     // 98304 B, stationary
    __shared__ float res_s[BGRP][HH_]; // 16384 B, restaged every step
    __shared__ float x_s[BGRP][128];   // 4096 B, restaged every 128 steps
    __shared__ float wih_s[48], bih_s[48], bhh_s[48];

    const int tid = threadIdx.x;
    const int bid = blockIdx.x;
    const int g   = bid >> 5;       // group
    const int j   = bid & 31;       // h-slice within group
    const int b0  = g * BGRP;
    const int h0  = j * HBLK;

    const int w    = tid >> 6;      // wave 0..7 -> h-pair {2w, 2w+1}
    const int lane = tid & 63;
    const int bg   = lane >> 4;     // batch-pair 0..3 -> b in {2bg, 2bg+1}
    const int ksub = lane & 15;     // k split 16-way

    unsigned* flags = (unsigned*)ws;               // [NGROUP*GBLK][FLAG_STRIDE]
    unsigned* grp_flags = flags + (size_t)g * GBLK * FLAG_STRIDE;
    float* resA = (float*)(ws + FLAG_BYTES);       // [B][H]
    float* resB = resA + BB_ * HH_;                // [B][H]

    // ---- stage stationary data ----
    #pragma unroll
    for (int gg = 0; gg < 3; ++gg)
        for (int i = tid; i < HBLK * HH_; i += NT) {
            int hl = i >> 9, k = i & 511;
            W_s[gg * 16 + hl][k] = W_hh[(size_t)(gg * HH_ + h0 + hl) * HH_ + k];
        }
    for (int i = tid; i < 48; i += NT) {
        int gg = i >> 4, hl = i & 15;
        int row = gg * HH_ + h0 + hl;
        wih_s[i] = W_ih[row];   // IN == 1
        bih_s[i] = b_ih[row];
        bhh_s[i] = b_hh[row];
    }
    const float Aval = A[0];

    // st accumulator lives on ksub==15 lanes: [bl][hh]
    float st[2][2];
    #pragma unroll
    for (int bl = 0; bl < 2; ++bl)
        #pragma unroll
        for (int hh = 0; hh < 2; ++hh)
            st[bl][hh] = state[(size_t)(b0 + 2 * bg + bl) * HH_ + h0 + 2 * w + hh];

    const float4* W4 = (const float4*)&W_s[0][0];
    const float4* R4 = (const float4*)&res_s[0][0];

    for (int t = 0; t < LL_; ++t) {
        // ---- stage x tile every 128 steps ----
        if ((t & 127) == 0) {
            for (int i = tid; i < BGRP * 128; i += NT) {
                int bb = i >> 7, kk = i & 127;
                x_s[bb][kk] = x[(size_t)(b0 + bb) * LL_ + t + kk];
            }
        }
        // ---- stage residual (8 b x 512) ----
        {
            float rv[BGRP];
            if (t == 0) {
                #pragma unroll
                for (int jj = 0; jj < BGRP; ++jj)
                    rv[jj] = state[(size_t)(b0 + jj) * HH_ + tid];
            } else {
                const float* rbuf = (t & 1) ? resB : resA;
                #pragma unroll
                for (int jj = 0; jj < BGRP; ++jj)
                    rv[jj] = __hip_atomic_load(&rbuf[(size_t)(b0 + jj) * HH_ + tid],
                                               __ATOMIC_RELAXED, __HIP_MEMORY_SCOPE_AGENT);
            }
            #pragma unroll
            for (int jj = 0; jj < BGRP; ++jj)
                res_s[jj][tid] = rv[jj];
        }
        __syncthreads();

        // ---- residual fragment to registers: 2 b x 8 chunks of float4 ----
        float4 rv4[2][8];
        #pragma unroll
        for (int bl = 0; bl < 2; ++bl)
            #pragma unroll
            for (int m = 0; m < 8; ++m)
                rv4[bl][m] = R4[(2 * bg + bl) * 128 + m * 16 + ksub];

        // ---- GEMM slice: acc[row6][bl2], k-partial over this lane's 32 k ----
        float acc[6][2];
        #pragma unroll
        for (int rr = 0; rr < 6; ++rr) { acc[rr][0] = 0.f; acc[rr][1] = 0.f; }

        #pragma unroll
        for (int rr = 0; rr < 6; ++rr) {
            const int gg = rr >> 1, hh = rr & 1;
            const int lr = gg * 16 + 2 * w + hh;
            #pragma unroll
            for (int m = 0; m < 8; ++m) {
                float4 wv = W4[lr * 128 + m * 16 + ksub];
                #pragma unroll
                for (int bl = 0; bl < 2; ++bl) {
                    float4 r = rv4[bl][m];
                    acc[rr][bl] += wv.x * r.x + wv.y * r.y + wv.z * r.z + wv.w * r.w;
                }
            }
        }

        // ---- reduce over ksub (16 lanes) via DPP row_shr; sum -> ksub==15 ----
        #pragma unroll
        for (int rr = 0; rr < 6; ++rr)
            #pragma unroll
            for (int bl = 0; bl < 2; ++bl) {
                float v = acc[rr][bl];
                v = dpp_add<0x111>(v);  // row_shr:1
                v = dpp_add<0x112>(v);  // row_shr:2
                v = dpp_add<0x114>(v);  // row_shr:4
                v = dpp_add<0x118>(v);  // row_shr:8
                acc[rr][bl] = v;
            }

        // ---- gates on ksub==15 lanes (4 per wave, 4 (b,h) outputs each) ----
        if (ksub == 15) {
            float* wbuf = (t & 1) ? resA : resB;
            #pragma unroll
            for (int bl = 0; bl < 2; ++bl) {
                const int b = 2 * bg + bl;
                const int bglob = b0 + b;
                const float xv = x_s[b][t & 127];
                #pragma unroll
                for (int hh = 0; hh < 2; ++hh) {
                    const int hl = 2 * w + hh;
                    const int hglob = h0 + hl;
                    float hr = acc[hh][bl]     + bhh_s[hl];
                    float hz = acc[2 + hh][bl] + bhh_s[16 + hl];
                    float hn = acc[4 + hh][bl] + bhh_s[32 + hl];
                    float ir = xv * wih_s[hl]      + bih_s[hl];
                    float iz = xv * wih_s[16 + hl] + bih_s[16 + hl];
                    float in_ = xv * wih_s[32 + hl] + bih_s[32 + hl];
                    float r = 1.f / (1.f + __expf(-(ir + hr)));
                    float z = 1.f / (1.f + __expf(-(iz + hz)));
                    float n = tanhf(in_ + r * hn);
                    float oldr = res_s[b][hglob];
                    float nr = (1.f - z) * n + z * oldr;
                    st[bl][hh] += Aval * nr;
                    __hip_atomic_store(&wbuf[(size_t)bglob * HH_ + hglob], nr,
                                       __ATOMIC_RELAXED, __HIP_MEMORY_SCOPE_AGENT);
                    out[((size_t)bglob * LL_ + t) * HH_ + hglob] = st[bl][hh];
                }
            }
        }

        // ---- group barrier: per-block flag slots + wave-0 ballot poll ----
        __syncthreads();   // drains vmcnt: residual stores are at MALL
        if (w == 0) {
            const unsigned target = (unsigned)(t + 1);
            if (lane == 0)
                __hip_atomic_store(&grp_flags[j * FLAG_STRIDE], target,
                                   __ATOMIC_RELEASE, __HIP_MEMORY_SCOPE_AGENT);
            unsigned v;
            do {
                v = (lane < GBLK)
                    ? __hip_atomic_load(&grp_flags[lane * FLAG_STRIDE],
                                        __ATOMIC_RELAXED, __HIP_MEMORY_SCOPE_AGENT)
                    : target;
            } while (!__all((int)(v >= target)));
        }
        __syncthreads();
    }

    // ---- final state ----
    if (ksub == 15) {
        #pragma unroll
        for (int bl = 0; bl < 2; ++bl)
            #pragma unroll
            for (int hh = 0; hh < 2; ++hh) {
                const int bglob = b0 + 2 * bg + bl;
                const int hglob = h0 + 2 * w + hh;
                out[(size_t)BB_ * LL_ * HH_ + (size_t)bglob * HH_ + hglob] = st[bl][hh];
            }
    }
}

extern "C" void kernel_launch(void* const* d_in, const int* in_sizes, int n_in,
                              void* d_out, int out_size, void* d_ws, size_t ws_size,
                              hipStream_t stream) {
    (void)in_sizes; (void)n_in; (void)out_size; (void)ws_size;
    const float* x     = (const float*)d_in[0];
    const float* state = (const float*)d_in[1];
    const float* W_ih  = (const float*)d_in[2];
    const float* W_hh  = (const float*)d_in[3];
    const float* b_ih  = (const float*)d_in[4];
    const float* b_hh  = (const float*)d_in[5];
    const float* A     = (const float*)d_in[6];

    // zero the flag array (d_ws is re-poisoned to 0xAA before every launch)
    hipMemsetAsync(d_ws, 0, FLAG_BYTES, stream);
    hipLaunchKernelGGL(gru_scan_kernel, dim3(NGROUP * GBLK), dim3(NT), 0, stream,
                       x, state, W_ih, W_hh, b_ih, b_hh, A,
                       (float*)d_out, (char*)d_ws);
}

// Round 3
// 10223.009 us; speedup vs baseline: 3.4344x; 2.3427x over previous
//
#include <hip/hip_runtime.h>
#include <math.h>

// GRU scan: B=64, L=2048, H=512, IN=1.
// 8 groups x 32 blocks; block j of group g holds W_hh rows for h-slice
// [16j,16j+16) (3 gates) stationary in LDS; group exchanges the 8-batch
// residual through d_ws each step.
//
// R3 changes (vs R2):
//  * residual exchange: per-element 4B atomics -> coalesced 16B coherent
//    global_load/store_dwordx4 sc0 sc1 (1M MALL ops/step -> ~70K).
//  * gate outputs staged in LDS, stored as full 64B lines (kills the
//    ~10x partial-line writeback amplification seen in WRITE_SIZE).
//  * `out` stores issued AFTER the flag release (overlap with poll).
//  * GEMM inner loop on v_pk_fma_f32 (2 MACs/inst, fp32-exact).
//  * res_s rows padded +4 floats -> uniform LDS bank use for b64 reads.

#define BB_ 64
#define LL_ 2048
#define HH_ 512
#define NGROUP 8
#define GBLK 32     // blocks per group
#define BGRP 8      // batches per group
#define HBLK 16     // h per block
#define NT 512      // threads per block
#define RROW (HH_ + 4)              // padded res_s row (floats)

#define FLAG_STRIDE 32              // dwords (128 B) per flag slot
#define FLAG_BYTES (NGROUP * GBLK * FLAG_STRIDE * 4)   // 32 KiB

typedef float f32x2 __attribute__((ext_vector_type(2)));
typedef float f32x4 __attribute__((ext_vector_type(4)));

template<int CTRL>
__device__ __forceinline__ float dpp_add(float x) {
    int s = __builtin_amdgcn_update_dpp(0, __float_as_int(x), CTRL, 0xF, 0xF, true);
    return x + __int_as_float(s);
}

__device__ __forceinline__ f32x4 load_f4_coherent(const float* p) {
    f32x4 r;
    asm volatile("global_load_dwordx4 %0, %1, off sc0 sc1" : "=v"(r) : "v"(p) : "memory");
    return r;
}
__device__ __forceinline__ void store_f4_coherent(float* p, f32x4 v) {
    asm volatile("global_store_dwordx4 %0, %1, off sc0 sc1" : : "v"(p), "v"(v) : "memory");
}
__device__ __forceinline__ void store_dw_coherent(unsigned* p, unsigned v) {
    asm volatile("global_store_dword %0, %1, off sc0 sc1" : : "v"(p), "v"(v) : "memory");
}
__device__ __forceinline__ void vm0() {
    asm volatile("s_waitcnt vmcnt(0)" ::: "memory");
    __builtin_amdgcn_sched_barrier(0);
}
__device__ __forceinline__ void pkfma(f32x2& acc, f32x2 a, f32x2 b) {
    asm("v_pk_fma_f32 %0, %1, %2, %0" : "+v"(acc) : "v"(a), "v"(b));
}

__global__ __launch_bounds__(NT, 2)
void gru_scan_kernel(const float* __restrict__ x,
                     const float* __restrict__ state,
                     const float* __restrict__ W_ih,
                     const float* __restrict__ W_hh,
                     const float* __restrict__ b_ih,
                     const float* __restrict__ b_hh,
                     const float* __restrict__ A,
                     float* __restrict__ out,
                     char* __restrict__ ws) {
    __shared__ float W_s[48][HH_];                    // 98304 B, stationary
    __shared__ __align__(16) float res_s[BGRP][RROW]; // 16512 B, restaged per step
    __shared__ float x_s[BGRP][128];                  // 4096 B, per 128 steps
    __shared__ float wih_s[48], bih_s[48], bhh_s[48];
    __shared__ __align__(16) float res_out_s[BGRP][HBLK];  // 512 B
    __shared__ __align__(16) float out_s[BGRP][HBLK];      // 512 B

    const int tid = threadIdx.x;
    const int bid = blockIdx.x;
    const int g   = bid >> 5;       // group
    const int j   = bid & 31;       // h-slice within group
    const int b0  = g * BGRP;
    const int h0  = j * HBLK;

    const int w    = tid >> 6;      // wave 0..7 -> h-pair {2w, 2w+1}
    const int lane = tid & 63;
    const int bg   = lane >> 4;     // batch-pair 0..3 -> b in {2bg, 2bg+1}
    const int ksub = lane & 15;     // k split 16-way

    unsigned* flags = (unsigned*)ws;               // [NGROUP*GBLK][FLAG_STRIDE]
    unsigned* grp_flags = flags + (size_t)g * GBLK * FLAG_STRIDE;
    float* resA = (float*)(ws + FLAG_BYTES);       // [B][H]
    float* resB = resA + BB_ * HH_;                // [B][H]

    // ---- stage stationary data ----
    #pragma unroll
    for (int gg = 0; gg < 3; ++gg)
        for (int i = tid; i < HBLK * HH_; i += NT) {
            int hl = i >> 9, k = i & 511;
            W_s[gg * 16 + hl][k] = W_hh[(size_t)(gg * HH_ + h0 + hl) * HH_ + k];
        }
    for (int i = tid; i < 48; i += NT) {
        int gg = i >> 4, hl = i & 15;
        int row = gg * HH_ + h0 + hl;
        wih_s[i] = W_ih[row];   // IN == 1
        bih_s[i] = b_ih[row];
        bhh_s[i] = b_hh[row];
    }
    const float Aval = A[0];

    // st accumulator lives on ksub==15 lanes: [bl][hh]
    float st[2][2];
    #pragma unroll
    for (int bl = 0; bl < 2; ++bl)
        #pragma unroll
        for (int hh = 0; hh < 2; ++hh)
            st[bl][hh] = state[(size_t)(b0 + 2 * bg + bl) * HH_ + h0 + 2 * w + hh];

    const f32x2* W2 = (const f32x2*)&W_s[0][0];
    const f32x2* R2 = (const f32x2*)&res_s[0][0];

    for (int t = 0; t < LL_; ++t) {
        // ---- stage x tile every 128 steps ----
        if ((t & 127) == 0) {
            for (int i = tid; i < BGRP * 128; i += NT) {
                int bb = i >> 7, kk = i & 127;
                x_s[bb][kk] = x[(size_t)(b0 + bb) * LL_ + t + kk];
            }
        }
        // ---- stage residual: 16 KB as 1024 float4, 2 per thread ----
        {
            const int c0 = tid, c1 = tid + NT;
            const int b_0 = c0 >> 7, q0 = c0 & 127;
            const int b_1 = c1 >> 7, q1 = c1 & 127;
            f32x4 v0, v1;
            if (t == 0) {
                v0 = *(const f32x4*)&state[(size_t)(b0 + b_0) * HH_ + q0 * 4];
                v1 = *(const f32x4*)&state[(size_t)(b0 + b_1) * HH_ + q1 * 4];
            } else {
                const float* rbuf = (t & 1) ? resB : resA;
                v0 = load_f4_coherent(&rbuf[(size_t)(b0 + b_0) * HH_ + q0 * 4]);
                v1 = load_f4_coherent(&rbuf[(size_t)(b0 + b_1) * HH_ + q1 * 4]);
                vm0();
            }
            *(f32x4*)&res_s[b_0][q0 * 4] = v0;
            *(f32x4*)&res_s[b_1][q1 * 4] = v1;
        }
        __syncthreads();   // (A)

        // ---- residual fragments to registers: [bl][16] f32x2 ----
        f32x2 rv2[2][16];
        #pragma unroll
        for (int bl = 0; bl < 2; ++bl) {
            const int rowb = (2 * bg + bl) * (RROW / 2);
            #pragma unroll
            for (int m = 0; m < 8; ++m) {
                rv2[bl][2 * m]     = R2[rowb + (m * 16 + ksub) * 2];
                rv2[bl][2 * m + 1] = R2[rowb + (m * 16 + ksub) * 2 + 1];
            }
        }

        // ---- GEMM slice via v_pk_fma_f32 ----
        f32x2 acc2[6][2];
        #pragma unroll
        for (int rr = 0; rr < 6; ++rr) {
            acc2[rr][0] = (f32x2){0.f, 0.f};
            acc2[rr][1] = (f32x2){0.f, 0.f};
        }
        #pragma unroll
        for (int rr = 0; rr < 6; ++rr) {
            const int gg = rr >> 1, hh = rr & 1;
            const int lr = gg * 16 + 2 * w + hh;
            #pragma unroll
            for (int m = 0; m < 8; ++m) {
                f32x2 w0 = W2[lr * 256 + (m * 16 + ksub) * 2];
                f32x2 w1 = W2[lr * 256 + (m * 16 + ksub) * 2 + 1];
                #pragma unroll
                for (int bl = 0; bl < 2; ++bl) {
                    pkfma(acc2[rr][bl], w0, rv2[bl][2 * m]);
                    pkfma(acc2[rr][bl], w1, rv2[bl][2 * m + 1]);
                }
            }
        }

        // ---- reduce: pair-sum then over ksub via DPP row_shr -> ksub==15 ----
        float acc[6][2];
        #pragma unroll
        for (int rr = 0; rr < 6; ++rr)
            #pragma unroll
            for (int bl = 0; bl < 2; ++bl) {
                float v = acc2[rr][bl].x + acc2[rr][bl].y;
                v = dpp_add<0x111>(v);  // row_shr:1
                v = dpp_add<0x112>(v);  // row_shr:2
                v = dpp_add<0x114>(v);  // row_shr:4
                v = dpp_add<0x118>(v);  // row_shr:8
                acc[rr][bl] = v;
            }

        // ---- gates on ksub==15 lanes; results -> LDS staging ----
        if (ksub == 15) {
            #pragma unroll
            for (int bl = 0; bl < 2; ++bl) {
                const int b = 2 * bg + bl;
                const float xv = x_s[b][t & 127];
                #pragma unroll
                for (int hh = 0; hh < 2; ++hh) {
                    const int hl = 2 * w + hh;
                    float hr = acc[hh][bl]     + bhh_s[hl];
                    float hz = acc[2 + hh][bl] + bhh_s[16 + hl];
                    float hn = acc[4 + hh][bl] + bhh_s[32 + hl];
                    float ir = xv * wih_s[hl]      + bih_s[hl];
                    float iz = xv * wih_s[16 + hl] + bih_s[16 + hl];
                    float in_ = xv * wih_s[32 + hl] + bih_s[32 + hl];
                    float r = 1.f / (1.f + __expf(-(ir + hr)));
                    float z = 1.f / (1.f + __expf(-(iz + hz)));
                    float n = tanhf(in_ + r * hn);
                    float oldr = res_s[b][h0 + hl];
                    float nr = (1.f - z) * n + z * oldr;
                    st[bl][hh] += Aval * nr;
                    res_out_s[b][hl] = nr;
                    out_s[b][hl] = st[bl][hh];
                }
            }
        }
        __syncthreads();   // (B) staging visible to wave 0

        if (w == 0) {
            float* wbuf = (t & 1) ? resA : resB;
            const unsigned target = (unsigned)(t + 1);
            // coherent residual store: 32 x 16B = full 64B lines
            if (lane < 32) {
                const int b = lane >> 2, p = lane & 3;
                store_f4_coherent(&wbuf[(size_t)(b0 + b) * HH_ + h0 + p * 4],
                                  *(f32x4*)&res_out_s[b][p * 4]);
            }
            vm0();                       // drain residual stores (wave 0 only)
            if (lane == 0)
                store_dw_coherent(&grp_flags[j * FLAG_STRIDE], target);
            // out stores: plain cached, issued after flag -> overlap poll
            if (lane < 32) {
                const int b = lane >> 2, p = lane & 3;
                *(f32x4*)&out[((size_t)(b0 + b) * LL_ + t) * HH_ + h0 + p * 4] =
                    *(f32x4*)&out_s[b][p * 4];
            }
            // poll all 32 flags of the group
            unsigned v;
            do {
                v = (lane < GBLK)
                    ? __hip_atomic_load(&grp_flags[lane * FLAG_STRIDE],
                                        __ATOMIC_RELAXED, __HIP_MEMORY_SCOPE_AGENT)
                    : target;
            } while (!__all((int)(v >= target)));
        }
        __syncthreads();   // (C)
    }

    // ---- final state ----
    if (ksub == 15) {
        #pragma unroll
        for (int bl = 0; bl < 2; ++bl)
            #pragma unroll
            for (int hh = 0; hh < 2; ++hh) {
                const int bglob = b0 + 2 * bg + bl;
                const int hglob = h0 + 2 * w + hh;
                out[(size_t)BB_ * LL_ * HH_ + (size_t)bglob * HH_ + hglob] = st[bl][hh];
            }
    }
}

extern "C" void kernel_launch(void* const* d_in, const int* in_sizes, int n_in,
                              void* d_out, int out_size, void* d_ws, size_t ws_size,
                              hipStream_t stream) {
    (void)in_sizes; (void)n_in; (void)out_size; (void)ws_size;
    const float* x     = (const float*)d_in[0];
    const float* state = (const float*)d_in[1];
    const float* W_ih  = (const float*)d_in[2];
    const float* W_hh  = (const float*)d_in[3];
    const float* b_ih  = (const float*)d_in[4];
    const float* b_hh  = (const float*)d_in[5];
    const float* A     = (const float*)d_in[6];

    // zero the flag array (d_ws is re-poisoned to 0xAA before every launch)
    hipMemsetAsync(d_ws, 0, FLAG_BYTES, stream);
    hipLaunchKernelGGL(gru_scan_kernel, dim3(NGROUP * GBLK), dim3(NT), 0, stream,
                       x, state, W_ih, W_hh, b_ih, b_hh, A,
                       (float*)d_out, (char*)d_ws);
}